// Round 13
// baseline (558.545 us; speedup 1.0000x reference)
//
#include <hip/hip_runtime.h>
#include <hip/hip_cooperative_groups.h>
#include <cmath>

namespace cg = cooperative_groups;

// B=256, T=48, N2=16, E=64, H=128, G=4H=512
// Block = (node n, batch-tile bt of 16). Gate weights resident in VGPRs as bf16
// MFMA B-frags; Ws/W_ho bf16 B-frags in LDS; c-state in registers; h bf16 in
// swizzled sXb; emb double-buffered. Cross-block exchange: psoc slots are
// self-validating {f32 val, u32 tag} u64s via the PROVEN 8B agent-scope atomic
// primitive. No flags, no drains, no L2 fences, no XCD assumptions (G16-safe).
// Tag for step t = t+1; consumer at step t wants tag == t in buffer (t-1)&1.

typedef __attribute__((ext_vector_type(8))) short bf16x8;
typedef __attribute__((ext_vector_type(4))) float f32x4;

__device__ __forceinline__ float fexp2(float x){ return __builtin_amdgcn_exp2f(x); }
__device__ __forceinline__ float frcp(float x){ return __builtin_amdgcn_rcpf(x); }
__device__ __forceinline__ float sigf(float x){ return frcp(1.0f + fexp2(-1.44269504f*x)); }
__device__ __forceinline__ float tanh_f(float x){ return 1.0f - 2.0f*frcp(1.0f + fexp2(2.88539008f*x)); }
__device__ __forceinline__ unsigned short f2bf(float f){
  unsigned u = __builtin_bit_cast(unsigned, f);
  return (unsigned short)((u + 0x7FFFu + ((u>>16)&1u)) >> 16);
}
__device__ __forceinline__ int ax(int b, int kb){ return (b<<9) + (kb ^ ((b&7)<<4)); }
__device__ __forceinline__ int axe(int b, int kb){ return (b<<7) + (kb ^ ((b&7)<<4)); }

// dynamic LDS partition (bytes)
#define OFF_WOF 0        // 32768: head B-frags
#define OFF_WSF 32768    // 16384: social B-frags
#define OFF_XB  49152    // 8192:  sXb bf16 [b][k=256] swizzled (pad|social|h)
#define OFF_EMB 57344    // 4096:  sEmbD: 2 x [16][128B] swizzled
#define OFF_RED 61440    // 8448:  red[16][132] fp32 (+ prologue scratch)
#define SMEM_BYTES 69888

__global__ __launch_bounds__(512, 2) void k_fused(
    const float* __restrict__ x, const float* __restrict__ Wd, const float* __restrict__ bd,
    const float* __restrict__ Ws, const float* __restrict__ bs,
    const float* __restrict__ W_ih, const float* __restrict__ b_ih,
    const float* __restrict__ W_hh, const float* __restrict__ b_hh,
    const float* __restrict__ W_ho, const float* __restrict__ b_ho,
    const float* __restrict__ W_out, const float* __restrict__ b_out,
    float* __restrict__ y,
    unsigned short* __restrict__ emb2b, unsigned long long* __restrict__ psoc64)
{
  extern __shared__ unsigned char smem[];
  unsigned char* sWoF  = smem + OFF_WOF;
  unsigned char* sWsF  = smem + OFF_WSF;
  unsigned char* sXb   = smem + OFF_XB;
  unsigned char* sEmbD = smem + OFF_EMB;
  float* red           = (float*)(smem + OFF_RED);

  const int bid = blockIdx.x, tid = threadIdx.x;
  const int lane = tid & 63, w = tid >> 6;
  cg::grid_group grid = cg::this_grid();

  const int n  = ((bid & 7) << 1) | ((bid >> 3) & 1);
  const int bt = bid >> 4, b0c = bt*16;

  // ---- zero tags of my write slots (both buffers): contiguous 1024 u64 each ----
  {
    unsigned long long* p0 = psoc64 + ((size_t)n*256 + b0c)*64;
    for (int j = tid; j < 1024; j += 512) {
      __hip_atomic_store(p0 + j,          0ull, __ATOMIC_RELAXED, __HIP_MEMORY_SCOPE_AGENT);
      __hip_atomic_store(p0 + 262144 + j, 0ull, __ATOMIC_RELAXED, __HIP_MEMORY_SCOPE_AGENT);
    }
  }

  // ---------- prologue A: downsample + embed, barrier-free (wave w: t = w+8*it) ----------
  {
    const float wd0 = Wd[lane], wd1 = Wd[64+lane], wd2 = Wd[128+lane], bde = bd[lane];
    float* scr = red + w*64;
    for (int it = 0; it < 6; ++it) {
      const int t = w + it*8;
      const float* xp = x + ((size_t)bid*48 + t)*4096;
      #pragma unroll
      for (int ci = 0; ci < 4; ++ci) {
        const float* rp = xp + (16*ci + (lane>>4))*64 + (lane&15)*4;
        float4 a0 = *(const float4*)(rp);
        float4 a1 = *(const float4*)(rp + 256);
        float4 a2 = *(const float4*)(rp + 512);
        float4 a3 = *(const float4*)(rp + 768);
        float sm = a0.x+a0.y+a0.z+a0.w + a1.x+a1.y+a1.z+a1.w
                 + a2.x+a2.y+a2.z+a2.w + a3.x+a3.y+a3.z+a3.w;
        float mx = fmaxf(fmaxf(fmaxf(fmaxf(a0.x,a0.y),fmaxf(a0.z,a0.w)),
                               fmaxf(fmaxf(a1.x,a1.y),fmaxf(a1.z,a1.w))),
                         fmaxf(fmaxf(fmaxf(a2.x,a2.y),fmaxf(a2.z,a2.w)),
                               fmaxf(fmaxf(a3.x,a3.y),fmaxf(a3.z,a3.w))));
        float mn = fminf(fminf(fminf(fminf(a0.x,a0.y),fminf(a0.z,a0.w)),
                               fminf(fminf(a1.x,a1.y),fminf(a1.z,a1.w))),
                         fminf(fminf(fminf(a2.x,a2.y),fminf(a2.z,a2.w)),
                               fminf(fminf(a3.x,a3.y),fminf(a3.z,a3.w))));
        #pragma unroll
        for (int m = 0; m < 4; ++m) {
          const int msk = (m<2) ? (1<<m) : (1<<(m+2));   // 1,2,16,32
          sm += __shfl_xor(sm, msk);
          mx = fmaxf(mx, __shfl_xor(mx, msk));
          mn = fminf(mn, __shfl_xor(mn, msk));
        }
        if (lane < 16 && (lane & 3) == 0) {
          int cj = lane >> 2;
          scr[(ci*4+cj)*3+0] = sm * (1.0f/256.0f);
          scr[(ci*4+cj)*3+1] = mx;
          scr[(ci*4+cj)*3+2] = mn;
        }
      }
      #pragma unroll
      for (int cell = 0; cell < 16; ++cell) {
        float vv = scr[cell*3]*wd0 + scr[cell*3+1]*wd1 + scr[cell*3+2]*wd2 + bde;
        emb2b[(((size_t)t*16 + cell)*256 + bid)*64 + lane] = f2bf(fmaxf(vv, 0.f));
      }
    }
  }

  // ---------- prologue B: pack Ws / W_ho into LDS as bf16 B-frags ----------
  __syncthreads();
  for (int s = tid; s < 1024; s += 512) {
    int wv = s >> 8, kt = (s >> 6) & 3, ln = s & 63;
    int e = wv*16 + (ln & 15), kb = kt*32 + (ln >> 4)*8;
    const float* src = Ws + (size_t)n*8192 + (size_t)kb*64 + e;
    bf16x8 v;
    #pragma unroll
    for (int j = 0; j < 8; ++j) v[j] = (short)f2bf(src[(size_t)j*64]);
    *(bf16x8*)&sWsF[s*16] = v;
  }
  for (int s = tid; s < 2048; s += 512) {
    int wv = s >> 8, kt = (s >> 6) & 3, ln = s & 63;
    int o = wv*16 + (ln & 15), kb = kt*32 + (ln >> 4)*8;
    const float* src = W_ho + (size_t)n*16384 + (size_t)kb*128 + o;
    bf16x8 v;
    #pragma unroll
    for (int j = 0; j < 8; ++j) v[j] = (short)f2bf(src[(size_t)j*128]);
    *(bf16x8*)&sWoF[s*16] = v;
  }

  // ---------- prologue C: resident bf16 gate B-frags + biases ----------
  const int hcol = w*16 + (lane & 15);
  bf16x8 bw[4][8];
  float bias[4];
  {
    const int krow = (lane >> 4)*8;
    #pragma unroll
    for (int G = 0; G < 4; ++G) {
      const float* srcI = W_ih + ((size_t)n*512 + G*128 + hcol)*128;
      const float* srcH = W_hh + ((size_t)n*512 + G*128 + hcol)*128;
      #pragma unroll
      for (int kt = 0; kt < 8; ++kt) {
        const float* s = (kt < 4) ? (srcI + kt*32 + krow) : (srcH + (kt-4)*32 + krow);
        float4 aa = *(const float4*)s;
        float4 bb = *(const float4*)(s+4);
        bf16x8 v;
        v[0]=(short)f2bf(aa.x); v[1]=(short)f2bf(aa.y); v[2]=(short)f2bf(aa.z); v[3]=(short)f2bf(aa.w);
        v[4]=(short)f2bf(bb.x); v[5]=(short)f2bf(bb.y); v[6]=(short)f2bf(bb.z); v[7]=(short)f2bf(bb.w);
        bw[G][kt] = v;
      }
      int gg = n*512 + G*128 + hcol;
      bias[G] = b_ih[gg] + b_hh[gg];
    }
  }
  { int b = tid >> 5, j = tid & 31;
    *(uint2*)&sXb[ax(b, 256 + j*8)] = make_uint2(0u, 0u); }

  asm volatile("s_waitcnt vmcnt(0)" ::: "memory");   // tag zeroes drained
  grid.sync();

  // ---------- per-thread maps ----------
  const int ocol = w*16 + (lane & 15);
  const float bho = b_ho[n*128 + ocol], wout = W_out[ocol];
  const float bout = b_out[0];
  const int sb = tid >> 5, sj = tid & 31, se2 = sj*2;
  const float bs0 = bs[se2], bs1 = bs[se2+1];
  float creg[4] = {0.f, 0.f, 0.f, 0.f};
  const int ab = lane & 15, akb = (lane >> 4)*16;

  // stage emb[t=0]
  { unsigned v = *(const unsigned*)&emb2b[(((size_t)0*16 + n)*256 + b0c + sb)*64 + se2];
    *(unsigned*)&sEmbD[axe(sb, sj*4)] = v; }
  __syncthreads();

  for (int t = 0; t < 48; ++t) {
    const unsigned char* sEmb = sEmbD + (t&1)*2048;

    // ---- gates partial MFMA: kt {0,1} (emb) + {4..7} (h) — block-local ----
    f32x4 acc[4];
    #pragma unroll
    for (int G = 0; G < 4; ++G) { f32x4 c0 = {bias[G], bias[G], bias[G], bias[G]}; acc[G] = c0; }
    #pragma unroll
    for (int kt = 0; kt < 2; ++kt) {
      bf16x8 aF = *(const bf16x8*)&sEmb[axe(ab, kt*64 + akb)];
      #pragma unroll
      for (int G = 0; G < 4; ++G)
        acc[G] = __builtin_amdgcn_mfma_f32_16x16x32_bf16(aF, bw[G][kt], acc[G], 0, 0, 0);
    }
    #pragma unroll
    for (int kt = 4; kt < 8; ++kt) {
      bf16x8 aF = *(const bf16x8*)&sXb[ax(ab, kt*64 + akb)];
      #pragma unroll
      for (int G = 0; G < 4; ++G)
        acc[G] = __builtin_amdgcn_mfma_f32_16x16x32_bf16(aF, bw[G][kt], acc[G], 0, 0, 0);
    }

    // ---- tag-validated social consume: one-shot per half, per-slot retry ----
    { float s0 = bs0, s1 = bs1;
      if (t > 0) {
        const unsigned want = (unsigned)t;
        const unsigned long long* pb =
          psoc64 + (size_t)((t-1)&1)*262144 + (size_t)(b0c + sb)*64 + se2;
        #pragma unroll
        for (int half = 0; half < 2; ++half) {
          unsigned long long v0[8], v1[8];
          #pragma unroll
          for (int k = 0; k < 8; ++k) {
            const size_t off = (size_t)(half*8 + k)*16384;
            v0[k] = __hip_atomic_load(pb + off,     __ATOMIC_RELAXED, __HIP_MEMORY_SCOPE_AGENT);
            v1[k] = __hip_atomic_load(pb + off + 1, __ATOMIC_RELAXED, __HIP_MEMORY_SCOPE_AGENT);
          }
          #pragma unroll
          for (int k = 0; k < 8; ++k) {
            const size_t off = (size_t)(half*8 + k)*16384;
            while ((unsigned)(v0[k] >> 32) != want) {
              __builtin_amdgcn_s_sleep(1);
              v0[k] = __hip_atomic_load(pb + off, __ATOMIC_RELAXED, __HIP_MEMORY_SCOPE_AGENT);
            }
            while ((unsigned)(v1[k] >> 32) != want) {
              __builtin_amdgcn_s_sleep(1);
              v1[k] = __hip_atomic_load(pb + off + 1, __ATOMIC_RELAXED, __HIP_MEMORY_SCOPE_AGENT);
            }
            s0 += __builtin_bit_cast(float, (unsigned)v0[k]);
            s1 += __builtin_bit_cast(float, (unsigned)v1[k]);
          }
        }
      }
      unsigned pk = (unsigned)f2bf(fmaxf(s0,0.f)) | ((unsigned)f2bf(fmaxf(s1,0.f)) << 16);
      *(unsigned*)&sXb[ax(sb, 128 + sj*4)] = pk; }
    __syncthreads();                                     // B3: social visible

    // ---- gates MFMA kt {2,3} (social) ----
    #pragma unroll
    for (int kt = 2; kt < 4; ++kt) {
      bf16x8 aF = *(const bf16x8*)&sXb[ax(ab, kt*64 + akb)];
      #pragma unroll
      for (int G = 0; G < 4; ++G)
        acc[G] = __builtin_amdgcn_mfma_f32_16x16x32_bf16(aF, bw[G][kt], acc[G], 0, 0, 0);
    }

    // ---- LSTM cell; write h (bf16) ----
    #pragma unroll
    for (int r = 0; r < 4; ++r) {
      int b = (lane >> 4)*4 + r;
      float cn = sigf(acc[1][r])*creg[r] + sigf(acc[0][r])*tanh_f(acc[2][r]);
      float hn = sigf(acc[3][r])*tanh_f(cn);
      creg[r] = cn;
      *(unsigned short*)&sXb[ax(b, 256 + hcol*2)] = f2bf(hn);
    }
    __syncthreads();                                     // B4: new h visible

    // ---- load h frags once ----
    bf16x8 aH[4];
    #pragma unroll
    for (int kt = 0; kt < 4; ++kt)
      aH[kt] = *(const bf16x8*)&sXb[ax(ab, 256 + kt*64 + akb)];

    // ---- social projection + tagged publish (stores fly under head MFMA) ----
    if (w < 4) {
      f32x4 ps = {0.f, 0.f, 0.f, 0.f};
      #pragma unroll
      for (int kt = 0; kt < 4; ++kt) {
        bf16x8 bs_ = *(const bf16x8*)&sWsF[((w*4 + kt)*64 + lane)*16];
        ps = __builtin_amdgcn_mfma_f32_16x16x32_bf16(aH[kt], bs_, ps, 0, 0, 0);
      }
      if (t < 47) {
        const unsigned long long tagu = (unsigned long long)(unsigned)(t+1) << 32;
        unsigned long long* pw = psoc64 + (size_t)(t&1)*262144 + (size_t)n*16384;
        const int ecol = w*16 + (lane & 15);
        #pragma unroll
        for (int r = 0; r < 4; ++r) {
          int b = b0c + (lane >> 4)*4 + r;
          unsigned long long u = (unsigned long long)__builtin_bit_cast(unsigned, ps[r]) | tagu;
          __hip_atomic_store(&pw[(size_t)b*64 + ecol], u, __ATOMIC_RELAXED, __HIP_MEMORY_SCOPE_AGENT);
        }
      }
    }

    // ---- head MFMA (all waves) + epilogue into red ----
    f32x4 ph = {bho, bho, bho, bho};
    #pragma unroll
    for (int kt = 0; kt < 4; ++kt) {
      bf16x8 bo = *(const bf16x8*)&sWoF[((w*4 + kt)*64 + lane)*16];
      ph = __builtin_amdgcn_mfma_f32_16x16x32_bf16(aH[kt], bo, ph, 0, 0, 0);
    }
    #pragma unroll
    for (int r = 0; r < 4; ++r) {
      int b = (lane >> 4)*4 + r;
      red[b*132 + ocol] = wout * sigf(ph[r]);
    }

    // ---- stage emb[t+1] ----
    if (t < 47) {
      unsigned v = *(const unsigned*)&emb2b[(((size_t)(t+1)*16 + n)*256 + b0c + sb)*64 + se2];
      *(unsigned*)&sEmbD[((t+1)&1)*2048 + axe(sb, sj*4)] = v;
    }

    __syncthreads();                                     // B6: end of step
    if (tid < 256) {
      int bb = tid >> 4, l = tid & 15;
      float sm = 0.f;
      #pragma unroll
      for (int kk = 0; kk < 8; ++kk) sm += red[bb*132 + l + 16*kk];
      #pragma unroll
      for (int m = 8; m >= 1; m >>= 1) sm += __shfl_xor(sm, m, 16);
      if (l == 0) y[((size_t)t*256 + b0c + bb)*16 + n] = sm + bout;
    }
  }
}

extern "C" void kernel_launch(void* const* d_in, const int* in_sizes, int n_in,
                              void* d_out, int out_size, void* d_ws, size_t ws_size,
                              hipStream_t stream){
  const float* x    = (const float*)d_in[0];
  const float* Wd   = (const float*)d_in[1];
  const float* bd   = (const float*)d_in[2];
  const float* Ws   = (const float*)d_in[3];
  const float* bs   = (const float*)d_in[4];
  const float* W_ih = (const float*)d_in[5];
  const float* b_ih = (const float*)d_in[6];
  const float* W_hh = (const float*)d_in[7];
  const float* b_hh = (const float*)d_in[8];
  const float* W_ho = (const float*)d_in[9];
  const float* b_ho = (const float*)d_in[10];
  const float* W_out= (const float*)d_in[11];
  const float* b_out= (const float*)d_in[12];
  float* y = (float*)d_out;

  char* ws = (char*)d_ws;
  unsigned short* emb2b = (unsigned short*)ws;                        // 25,165,824 B
  unsigned long long* psoc64 = (unsigned long long*)(ws + 25165824);  // 4,194,304 B

  hipFuncSetAttribute((const void*)k_fused, hipFuncAttributeMaxDynamicSharedMemorySize, SMEM_BYTES);

  void* args[] = { (void*)&x, (void*)&Wd, (void*)&bd, (void*)&Ws, (void*)&bs,
                   (void*)&W_ih, (void*)&b_ih, (void*)&W_hh, (void*)&b_hh,
                   (void*)&W_ho, (void*)&b_ho, (void*)&W_out, (void*)&b_out,
                   (void*)&y, (void*)&emb2b, (void*)&psoc64 };
  hipLaunchCooperativeKernel((const void*)k_fused, dim3(256), dim3(512), args, SMEM_BYTES, stream);
}

// Round 14
// 427.170 us; speedup vs baseline: 1.3075x; 1.3075x over previous
//
#include <hip/hip_runtime.h>
#include <hip/hip_cooperative_groups.h>
#include <cmath>

namespace cg = cooperative_groups;

// B=256, T=48, N2=16, E=64, H=128, G=4H=512
// Block = (node n, batch-tile bt of 16). Round-10 proven flag+psoc protocol
// (sc1 data, per-wave flags w/ own vmcnt drain, 64->128-lane poll).
// NEW: downsample+embed pipelined into the loop with K=2 lookahead:
// waves 4-7 compute emb[t+2] (x loads issued at step start), publish via sc1
// 8B stores, certify with their per-wave flags. Prologue A = 2 timesteps only.

typedef __attribute__((ext_vector_type(8))) short bf16x8;
typedef __attribute__((ext_vector_type(4))) float f32x4;

__device__ __forceinline__ float fexp2(float x){ return __builtin_amdgcn_exp2f(x); }
__device__ __forceinline__ float frcp(float x){ return __builtin_amdgcn_rcpf(x); }
__device__ __forceinline__ float sigf(float x){ return frcp(1.0f + fexp2(-1.44269504f*x)); }
__device__ __forceinline__ float tanh_f(float x){ return 1.0f - 2.0f*frcp(1.0f + fexp2(2.88539008f*x)); }
__device__ __forceinline__ unsigned short f2bf(float f){
  unsigned u = __builtin_bit_cast(unsigned, f);
  return (unsigned short)((u + 0x7FFFu + ((u>>16)&1u)) >> 16);
}
__device__ __forceinline__ int ax(int b, int kb){ return (b<<9) + (kb ^ ((b&7)<<4)); }
__device__ __forceinline__ int axe(int b, int kb){ return (b<<7) + (kb ^ ((b&7)<<4)); }

// dynamic LDS partition (bytes)
#define OFF_WOF  0        // 32768: head B-frags
#define OFF_WSF  32768    // 16384: social B-frags
#define OFF_XB   49152    // 8192:  sXb bf16 [b][k=256] swizzled (pad|social|h)
#define OFF_EMB  57344    // 4096:  sEmbD: 2 x [16][128B] swizzled
#define OFF_RED  61440    // 8448:  red[16][132] fp32 (+ prologue scratch)
#define OFF_ESCR 69888    // 2304:  emb scratch, 4 waves x (64B stats + 512B pack)
#define SMEM_BYTES 72192

__global__ __launch_bounds__(512, 2) void k_fused(
    const float* __restrict__ x, const float* __restrict__ Wd, const float* __restrict__ bd,
    const float* __restrict__ Ws, const float* __restrict__ bs,
    const float* __restrict__ W_ih, const float* __restrict__ b_ih,
    const float* __restrict__ W_hh, const float* __restrict__ b_hh,
    const float* __restrict__ W_ho, const float* __restrict__ b_ho,
    const float* __restrict__ W_out, const float* __restrict__ b_out,
    float* __restrict__ y,
    unsigned short* __restrict__ emb2b, float* __restrict__ psoc, int* __restrict__ flagv)
{
  extern __shared__ unsigned char smem[];
  unsigned char* sWoF  = smem + OFF_WOF;
  unsigned char* sWsF  = smem + OFF_WSF;
  unsigned char* sXb   = smem + OFF_XB;
  unsigned char* sEmbD = smem + OFF_EMB;
  float* red           = (float*)(smem + OFF_RED);

  const int bid = blockIdx.x, tid = threadIdx.x;
  const int lane = tid & 63, w = tid >> 6;
  cg::grid_group grid = cg::this_grid();

  const int n  = ((bid & 7) << 1) | ((bid >> 3) & 1);
  const int bt = bid >> 4, b0c = bt*16;

  // ---- zero my per-wave flag slots: [t][bt][n*8+w], 16B padded (48t x 8w) ----
  for (int j = tid; j < 384; j += 512)
    __hip_atomic_store(&flagv[(((j>>3)*16 + bt)*128 + n*8 + (j&7))*4], 0,
                       __ATOMIC_RELAXED, __HIP_MEMORY_SCOPE_AGENT);

  const float wd0 = Wd[lane], wd1 = Wd[64+lane], wd2 = Wd[128+lane], bde = bd[lane];

  // ---------- prologue A': emb[0], emb[1] only (wave w: t2=w>>2, ci=w&3) ----------
  {
    const int t2 = w >> 2, cw = w & 3;
    const float* rp = x + ((size_t)bid*48 + t2)*4096 + (16*cw + (lane>>4))*64 + (lane&15)*4;
    float4 a0 = *(const float4*)(rp);
    float4 a1 = *(const float4*)(rp + 256);
    float4 a2 = *(const float4*)(rp + 512);
    float4 a3 = *(const float4*)(rp + 768);
    float sm = a0.x+a0.y+a0.z+a0.w + a1.x+a1.y+a1.z+a1.w
             + a2.x+a2.y+a2.z+a2.w + a3.x+a3.y+a3.z+a3.w;
    float mx = fmaxf(fmaxf(fmaxf(fmaxf(a0.x,a0.y),fmaxf(a0.z,a0.w)),
                           fmaxf(fmaxf(a1.x,a1.y),fmaxf(a1.z,a1.w))),
                     fmaxf(fmaxf(fmaxf(a2.x,a2.y),fmaxf(a2.z,a2.w)),
                           fmaxf(fmaxf(a3.x,a3.y),fmaxf(a3.z,a3.w))));
    float mn = fminf(fminf(fminf(fminf(a0.x,a0.y),fminf(a0.z,a0.w)),
                           fminf(fminf(a1.x,a1.y),fminf(a1.z,a1.w))),
                     fminf(fminf(fminf(a2.x,a2.y),fminf(a2.z,a2.w)),
                           fminf(fminf(a3.x,a3.y),fminf(a3.z,a3.w))));
    #pragma unroll
    for (int m = 0; m < 4; ++m) {
      const int msk = (m<2) ? (1<<m) : (1<<(m+2));   // 1,2,16,32
      sm += __shfl_xor(sm, msk);
      mx = fmaxf(mx, __shfl_xor(mx, msk));
      mn = fminf(mn, __shfl_xor(mn, msk));
    }
    float* scr = red + w*64;
    if (lane < 16 && (lane & 3) == 0) {
      int cj = lane >> 2;
      scr[cj*3+0] = sm * (1.0f/256.0f); scr[cj*3+1] = mx; scr[cj*3+2] = mn;
    }
    #pragma unroll
    for (int cj = 0; cj < 4; ++cj) {
      float vv = scr[cj*3]*wd0 + scr[cj*3+1]*wd1 + scr[cj*3+2]*wd2 + bde;
      emb2b[(((size_t)t2*16 + 4*cw+cj)*256 + bid)*64 + lane] = f2bf(fmaxf(vv, 0.f));
    }
  }
  __syncthreads();

  // ---------- prologue B: pack Ws / W_ho into LDS as bf16 B-frags ----------
  for (int s = tid; s < 1024; s += 512) {
    int wv = s >> 8, kt = (s >> 6) & 3, ln = s & 63;
    int e = wv*16 + (ln & 15), kb = kt*32 + (ln >> 4)*8;
    const float* src = Ws + (size_t)n*8192 + (size_t)kb*64 + e;
    bf16x8 v;
    #pragma unroll
    for (int j = 0; j < 8; ++j) v[j] = (short)f2bf(src[(size_t)j*64]);
    *(bf16x8*)&sWsF[s*16] = v;
  }
  for (int s = tid; s < 2048; s += 512) {
    int wv = s >> 8, kt = (s >> 6) & 3, ln = s & 63;
    int o = wv*16 + (ln & 15), kb = kt*32 + (ln >> 4)*8;
    const float* src = W_ho + (size_t)n*16384 + (size_t)kb*128 + o;
    bf16x8 v;
    #pragma unroll
    for (int j = 0; j < 8; ++j) v[j] = (short)f2bf(src[(size_t)j*128]);
    *(bf16x8*)&sWoF[s*16] = v;
  }

  // ---------- prologue C: resident bf16 gate B-frags + biases ----------
  const int hcol = w*16 + (lane & 15);
  bf16x8 bw[4][8];
  float bias[4];
  {
    const int krow = (lane >> 4)*8;
    #pragma unroll
    for (int G = 0; G < 4; ++G) {
      const float* srcI = W_ih + ((size_t)n*512 + G*128 + hcol)*128;
      const float* srcH = W_hh + ((size_t)n*512 + G*128 + hcol)*128;
      #pragma unroll
      for (int kt = 0; kt < 8; ++kt) {
        const float* s = (kt < 4) ? (srcI + kt*32 + krow) : (srcH + (kt-4)*32 + krow);
        float4 aa = *(const float4*)s;
        float4 bb = *(const float4*)(s+4);
        bf16x8 v;
        v[0]=(short)f2bf(aa.x); v[1]=(short)f2bf(aa.y); v[2]=(short)f2bf(aa.z); v[3]=(short)f2bf(aa.w);
        v[4]=(short)f2bf(bb.x); v[5]=(short)f2bf(bb.y); v[6]=(short)f2bf(bb.z); v[7]=(short)f2bf(bb.w);
        bw[G][kt] = v;
      }
      int gg = n*512 + G*128 + hcol;
      bias[G] = b_ih[gg] + b_hh[gg];
    }
  }
  { int b = tid >> 5, j = tid & 31;
    *(uint2*)&sXb[ax(b, 256 + j*8)] = make_uint2(0u, 0u); }

  asm volatile("s_waitcnt vmcnt(0)" ::: "memory");   // flag zeroes drained
  grid.sync();

  // ---------- per-thread maps ----------
  const int ocol = w*16 + (lane & 15);
  const float bho = b_ho[n*128 + ocol], wout = W_out[ocol];
  const float bout = b_out[0];
  const int sb = tid >> 5, sj = tid & 31, se2 = sj*2;
  const float bs0 = bs[se2], bs1 = bs[se2+1];
  float creg[4] = {0.f, 0.f, 0.f, 0.f};
  const int ab = lane & 15, akb = (lane >> 4)*16;
  unsigned long long* emb64 = (unsigned long long*)emb2b;

  // stage emb[t=0] into buffer 0
  { unsigned v = *(const unsigned*)&emb2b[(((size_t)0*16 + n)*256 + b0c + sb)*64 + se2];
    *(unsigned*)&sEmbD[axe(sb, sj*4)] = v; }
  __syncthreads();

  for (int t = 0; t < 48; ++t) {
    const unsigned char* sEmb = sEmbD + (t&1)*2048;

    // ---- issue x loads for emb[t+2] (waves 4-7); latency hides under the step ----
    float4 xa0, xa1, xa2, xa3;
    const bool doEmb = (w >= 4) && (t < 46);
    if (doEmb) {
      const float* rp = x + ((size_t)bid*48 + (t+2))*4096 + (16*(w-4) + (lane>>4))*64 + (lane&15)*4;
      xa0 = *(const float4*)(rp);
      xa1 = *(const float4*)(rp + 256);
      xa2 = *(const float4*)(rp + 512);
      xa3 = *(const float4*)(rp + 768);
    }

    // ---- gates partial MFMA: kt {0,1} (emb) + {4..7} (h) — block-local ----
    f32x4 acc[4];
    #pragma unroll
    for (int G = 0; G < 4; ++G) { f32x4 c0 = {bias[G], bias[G], bias[G], bias[G]}; acc[G] = c0; }
    #pragma unroll
    for (int kt = 0; kt < 2; ++kt) {
      bf16x8 aF = *(const bf16x8*)&sEmb[axe(ab, kt*64 + akb)];
      #pragma unroll
      for (int G = 0; G < 4; ++G)
        acc[G] = __builtin_amdgcn_mfma_f32_16x16x32_bf16(aF, bw[G][kt], acc[G], 0, 0, 0);
    }
    #pragma unroll
    for (int kt = 4; kt < 8; ++kt) {
      bf16x8 aF = *(const bf16x8*)&sXb[ax(ab, kt*64 + akb)];
      #pragma unroll
      for (int G = 0; G < 4; ++G)
        acc[G] = __builtin_amdgcn_mfma_f32_16x16x32_bf16(aF, bw[G][kt], acc[G], 0, 0, 0);
    }

    // ---- poll previous step's 128 per-wave flags (waves 0-1, one slot each) ----
    if (t > 0 && tid < 128) {
      const int* fp = &flagv[(((t-1)*16 + bt)*128 + tid)*4];
      int f0 = __hip_atomic_load(fp, __ATOMIC_RELAXED, __HIP_MEMORY_SCOPE_AGENT);
      while (!f0) {
        __builtin_amdgcn_s_sleep(1);
        f0 = __hip_atomic_load(fp, __ATOMIC_RELAXED, __HIP_MEMORY_SCOPE_AGENT);
      }
    }
    __syncthreads();                                     // B2: producers done

    // ---- social reduce (16 x 8B sc1 loads) -> relu -> bf16 stage ----
    { float s0 = bs0, s1 = bs1;
      if (t > 0) {
        const unsigned long long* pb = (const unsigned long long*)
          (psoc + (size_t)((t-1)&1)*1048576 + (size_t)(b0c + sb)*64 + se2);
        unsigned long long v[16];
        #pragma unroll
        for (int nn = 0; nn < 16; ++nn)
          v[nn] = __hip_atomic_load(pb + (size_t)nn*8192, __ATOMIC_RELAXED, __HIP_MEMORY_SCOPE_AGENT);
        #pragma unroll
        for (int nn = 0; nn < 16; ++nn) {
          float2 f2 = __builtin_bit_cast(float2, v[nn]);
          s0 += f2.x; s1 += f2.y;
        }
      }
      unsigned pk = (unsigned)f2bf(fmaxf(s0,0.f)) | ((unsigned)f2bf(fmaxf(s1,0.f)) << 16);
      *(unsigned*)&sXb[ax(sb, 128 + sj*4)] = pk; }
    __syncthreads();                                     // B3: social visible

    // ---- gates MFMA kt {2,3} (social) ----
    #pragma unroll
    for (int kt = 2; kt < 4; ++kt) {
      bf16x8 aF = *(const bf16x8*)&sXb[ax(ab, kt*64 + akb)];
      #pragma unroll
      for (int G = 0; G < 4; ++G)
        acc[G] = __builtin_amdgcn_mfma_f32_16x16x32_bf16(aF, bw[G][kt], acc[G], 0, 0, 0);
    }

    // ---- LSTM cell; write h (bf16) ----
    #pragma unroll
    for (int r = 0; r < 4; ++r) {
      int b = (lane >> 4)*4 + r;
      float cn = sigf(acc[1][r])*creg[r] + sigf(acc[0][r])*tanh_f(acc[2][r]);
      float hn = sigf(acc[3][r])*tanh_f(cn);
      creg[r] = cn;
      *(unsigned short*)&sXb[ax(b, 256 + hcol*2)] = f2bf(hn);
    }
    __syncthreads();                                     // B4: new h visible

    // ---- load h frags once ----
    bf16x8 aH[4];
    #pragma unroll
    for (int kt = 0; kt < 4; ++kt)
      aH[kt] = *(const bf16x8*)&sXb[ax(ab, 256 + kt*64 + akb)];

    // ---- waves 0-3: social projection + psoc publish (sc1) ----
    if (w < 4) {
      f32x4 ps = {0.f, 0.f, 0.f, 0.f};
      #pragma unroll
      for (int kt = 0; kt < 4; ++kt) {
        bf16x8 bs_ = *(const bf16x8*)&sWsF[((w*4 + kt)*64 + lane)*16];
        ps = __builtin_amdgcn_mfma_f32_16x16x32_bf16(aH[kt], bs_, ps, 0, 0, 0);
      }
      if (t < 47) {
        float* pw = psoc + (size_t)(t&1)*1048576 + (size_t)n*16384;
        const int ecol = w*16 + (lane & 15);
        #pragma unroll
        for (int r = 0; r < 4; ++r) {
          int b = b0c + (lane >> 4)*4 + r;
          __hip_atomic_store(&pw[(size_t)b*64 + ecol], ps[r], __ATOMIC_RELAXED, __HIP_MEMORY_SCOPE_AGENT);
        }
      }
    } else if (doEmb) {
      // ---- waves 4-7: downsample + embed emb[t+2], publish (sc1 8B) ----
      float sm = xa0.x+xa0.y+xa0.z+xa0.w + xa1.x+xa1.y+xa1.z+xa1.w
               + xa2.x+xa2.y+xa2.z+xa2.w + xa3.x+xa3.y+xa3.z+xa3.w;
      float mx = fmaxf(fmaxf(fmaxf(fmaxf(xa0.x,xa0.y),fmaxf(xa0.z,xa0.w)),
                             fmaxf(fmaxf(xa1.x,xa1.y),fmaxf(xa1.z,xa1.w))),
                       fmaxf(fmaxf(fmaxf(xa2.x,xa2.y),fmaxf(xa2.z,xa2.w)),
                             fmaxf(fmaxf(xa3.x,xa3.y),fmaxf(xa3.z,xa3.w))));
      float mn = fminf(fminf(fminf(fminf(xa0.x,xa0.y),fminf(xa0.z,xa0.w)),
                             fminf(fminf(xa1.x,xa1.y),fminf(xa1.z,xa1.w))),
                       fminf(fminf(fminf(xa2.x,xa2.y),fminf(xa2.z,xa2.w)),
                             fminf(fminf(xa3.x,xa3.y),fminf(xa3.z,xa3.w))));
      #pragma unroll
      for (int m = 0; m < 4; ++m) {
        const int msk = (m<2) ? (1<<m) : (1<<(m+2));   // 1,2,16,32
        sm += __shfl_xor(sm, msk);
        mx = fmaxf(mx, __shfl_xor(mx, msk));
        mn = fminf(mn, __shfl_xor(mn, msk));
      }
      float* scrS = (float*)(smem + OFF_ESCR + (size_t)(w-4)*576);
      unsigned short* scrP = (unsigned short*)(smem + OFF_ESCR + (size_t)(w-4)*576 + 64);
      if (lane < 16 && (lane & 3) == 0) {
        int cj = lane >> 2;
        scrS[cj*3+0] = sm * (1.0f/256.0f); scrS[cj*3+1] = mx; scrS[cj*3+2] = mn;
      }
      #pragma unroll
      for (int cj = 0; cj < 4; ++cj) {
        float vv = scrS[cj*3]*wd0 + scrS[cj*3+1]*wd1 + scrS[cj*3+2]*wd2 + bde;
        scrP[cj*64 + lane] = f2bf(fmaxf(vv, 0.f));
      }
      unsigned long long u = *(const unsigned long long*)&scrP[lane*4];
      const int cell = 4*(w-4) + (lane >> 4);
      const size_t dst = (((size_t)(t+2)*16 + cell)*256 + bid)*16 + (lane & 15);
      __hip_atomic_store(&emb64[dst], u, __ATOMIC_RELAXED, __HIP_MEMORY_SCOPE_AGENT);
    }

    // ---- head MFMA (all waves) + epilogue into red (stores fly underneath) ----
    f32x4 ph = {bho, bho, bho, bho};
    #pragma unroll
    for (int kt = 0; kt < 4; ++kt) {
      bf16x8 bo = *(const bf16x8*)&sWoF[((w*4 + kt)*64 + lane)*16];
      ph = __builtin_amdgcn_mfma_f32_16x16x32_bf16(aH[kt], bo, ph, 0, 0, 0);
    }
    #pragma unroll
    for (int r = 0; r < 4; ++r) {
      int b = (lane >> 4)*4 + r;
      red[b*132 + ocol] = wout * sigf(ph[r]);
    }

    // ---- per-wave drain + per-wave flag (all 8 waves) ----
    if (t < 47) {
      asm volatile("s_waitcnt vmcnt(0)" ::: "memory");   // this wave's sc1 stores done
      if (lane == 0)
        __hip_atomic_store(&flagv[((t*16 + bt)*128 + n*8 + w)*4], 1,
                           __ATOMIC_RELAXED, __HIP_MEMORY_SCOPE_AGENT);
    }

    // ---- stage emb[t+1] (certified by flag[t-1], K=2) ----
    if (t < 47) {
      unsigned v = *(const unsigned*)&emb2b[(((size_t)(t+1)*16 + n)*256 + b0c + sb)*64 + se2];
      *(unsigned*)&sEmbD[((t+1)&1)*2048 + axe(sb, sj*4)] = v;
    }

    __syncthreads();                                     // B6: end of step
    if (tid < 256) {
      int bb = tid >> 4, l = tid & 15;
      float sm2 = 0.f;
      #pragma unroll
      for (int kk = 0; kk < 8; ++kk) sm2 += red[bb*132 + l + 16*kk];
      #pragma unroll
      for (int m = 8; m >= 1; m >>= 1) sm2 += __shfl_xor(sm2, m, 16);
      if (l == 0) y[((size_t)t*256 + b0c + bb)*16 + n] = sm2 + bout;
    }
  }
}

extern "C" void kernel_launch(void* const* d_in, const int* in_sizes, int n_in,
                              void* d_out, int out_size, void* d_ws, size_t ws_size,
                              hipStream_t stream){
  const float* x    = (const float*)d_in[0];
  const float* Wd   = (const float*)d_in[1];
  const float* bd   = (const float*)d_in[2];
  const float* Ws   = (const float*)d_in[3];
  const float* bs   = (const float*)d_in[4];
  const float* W_ih = (const float*)d_in[5];
  const float* b_ih = (const float*)d_in[6];
  const float* W_hh = (const float*)d_in[7];
  const float* b_hh = (const float*)d_in[8];
  const float* W_ho = (const float*)d_in[9];
  const float* b_ho = (const float*)d_in[10];
  const float* W_out= (const float*)d_in[11];
  const float* b_out= (const float*)d_in[12];
  float* y = (float*)d_out;

  char* ws = (char*)d_ws;
  unsigned short* emb2b = (unsigned short*)ws;          // 25,165,824 B
  float* psoc  = (float*)(ws + 25165824);               // 8,388,608 B (2 buf)
  int*   flagv = (int*)(ws + 25165824 + 8388608);       // 393,216 B (48*16*128 slots, 16B padded)

  hipFuncSetAttribute((const void*)k_fused, hipFuncAttributeMaxDynamicSharedMemorySize, SMEM_BYTES);

  void* args[] = { (void*)&x, (void*)&Wd, (void*)&bd, (void*)&Ws, (void*)&bs,
                   (void*)&W_ih, (void*)&b_ih, (void*)&W_hh, (void*)&b_hh,
                   (void*)&W_ho, (void*)&b_ho, (void*)&W_out, (void*)&b_out,
                   (void*)&y, (void*)&emb2b, (void*)&psoc, (void*)&flagv };
  hipLaunchCooperativeKernel((const void*)k_fused, dim3(256), dim3(512), args, SMEM_BYTES, stream);
}

// Round 15
// 314.408 us; speedup vs baseline: 1.7765x; 1.3586x over previous
//
#include <hip/hip_runtime.h>
#include <hip/hip_cooperative_groups.h>
#include <cmath>

namespace cg = cooperative_groups;

// B=256, T=48, N2=16, E=64, H=128, G=4H=512
// Block = (node n, batch-tile bt of 16). Round-10 proven protocol: psoc f32 sc1
// slots, per-wave producer flags (own vmcnt drain + lane0 store), 64-lane poll.
// This round: 3 barriers/step (y-reduce of t-1 and emb stage folded into step t,
// hidden under mailbox RTT), flag issued before head MFMA, prologue load hoist.

typedef __attribute__((ext_vector_type(8))) short bf16x8;
typedef __attribute__((ext_vector_type(4))) float f32x4;

__device__ __forceinline__ float fexp2(float x){ return __builtin_amdgcn_exp2f(x); }
__device__ __forceinline__ float frcp(float x){ return __builtin_amdgcn_rcpf(x); }
__device__ __forceinline__ float sigf(float x){ return frcp(1.0f + fexp2(-1.44269504f*x)); }
__device__ __forceinline__ float tanh_f(float x){ return 1.0f - 2.0f*frcp(1.0f + fexp2(2.88539008f*x)); }
__device__ __forceinline__ unsigned short f2bf(float f){
  unsigned u = __builtin_bit_cast(unsigned, f);
  return (unsigned short)((u + 0x7FFFu + ((u>>16)&1u)) >> 16);
}
__device__ __forceinline__ int ax(int b, int kb){ return (b<<9) + (kb ^ ((b&7)<<4)); }
__device__ __forceinline__ int axe(int b, int kb){ return (b<<7) + (kb ^ ((b&7)<<4)); }

// dynamic LDS partition (bytes)
#define OFF_WOF 0        // 32768: head B-frags
#define OFF_WSF 32768    // 16384: social B-frags
#define OFF_XB  49152    // 8192:  sXb bf16 [b][k=256] swizzled (pad|social|h)
#define OFF_EMB 57344    // 4096:  sEmbD: 2 x [16][128B] swizzled
#define OFF_RED 61440    // 8448:  red[16][132] fp32 (+ prologue scratch)
#define SMEM_BYTES 69888

__global__ __launch_bounds__(512, 2) void k_fused(
    const float* __restrict__ x, const float* __restrict__ Wd, const float* __restrict__ bd,
    const float* __restrict__ Ws, const float* __restrict__ bs,
    const float* __restrict__ W_ih, const float* __restrict__ b_ih,
    const float* __restrict__ W_hh, const float* __restrict__ b_hh,
    const float* __restrict__ W_ho, const float* __restrict__ b_ho,
    const float* __restrict__ W_out, const float* __restrict__ b_out,
    float* __restrict__ y,
    unsigned short* __restrict__ emb2b, float* __restrict__ psoc, int* __restrict__ flagv)
{
  extern __shared__ unsigned char smem[];
  unsigned char* sWoF  = smem + OFF_WOF;
  unsigned char* sWsF  = smem + OFF_WSF;
  unsigned char* sXb   = smem + OFF_XB;
  unsigned char* sEmbD = smem + OFF_EMB;
  float* red           = (float*)(smem + OFF_RED);

  const int bid = blockIdx.x, tid = threadIdx.x;
  const int lane = tid & 63, w = tid >> 6;
  cg::grid_group grid = cg::this_grid();

  const int n  = ((bid & 7) << 1) | ((bid >> 3) & 1);
  const int bt = bid >> 4, b0c = bt*16;

  // ---- zero my per-wave flag slots: [t][bt][n][w], 16B padded ----
  for (int j = tid; j < 192; j += 512)   // j = t*4 + w
    __hip_atomic_store(&flagv[(((j>>2)*16 + bt)*64 + n*4 + (j&3))*4], 0,
                       __ATOMIC_RELAXED, __HIP_MEMORY_SCOPE_AGENT);

  // ---------- prologue A: downsample + embed, barrier-free (wave w: t = w+8*it) ----------
  {
    const float wd0 = Wd[lane], wd1 = Wd[64+lane], wd2 = Wd[128+lane], bde = bd[lane];
    float* scr = red + w*64;   // per-wave scratch
    for (int it = 0; it < 6; ++it) {
      const int t = w + it*8;
      const float* xp = x + ((size_t)bid*48 + t)*4096;
      float4 xv[4][4];
      #pragma unroll
      for (int ci = 0; ci < 4; ++ci) {           // hoist all 16 loads
        const float* rp = xp + (16*ci + (lane>>4))*64 + (lane&15)*4;
        xv[ci][0] = *(const float4*)(rp);
        xv[ci][1] = *(const float4*)(rp + 256);
        xv[ci][2] = *(const float4*)(rp + 512);
        xv[ci][3] = *(const float4*)(rp + 768);
      }
      #pragma unroll
      for (int ci = 0; ci < 4; ++ci) {
        float4 a0 = xv[ci][0], a1 = xv[ci][1], a2 = xv[ci][2], a3 = xv[ci][3];
        float sm = a0.x+a0.y+a0.z+a0.w + a1.x+a1.y+a1.z+a1.w
                 + a2.x+a2.y+a2.z+a2.w + a3.x+a3.y+a3.z+a3.w;
        float mx = fmaxf(fmaxf(fmaxf(fmaxf(a0.x,a0.y),fmaxf(a0.z,a0.w)),
                               fmaxf(fmaxf(a1.x,a1.y),fmaxf(a1.z,a1.w))),
                         fmaxf(fmaxf(fmaxf(a2.x,a2.y),fmaxf(a2.z,a2.w)),
                               fmaxf(fmaxf(a3.x,a3.y),fmaxf(a3.z,a3.w))));
        float mn = fminf(fminf(fminf(fminf(a0.x,a0.y),fminf(a0.z,a0.w)),
                               fminf(fminf(a1.x,a1.y),fminf(a1.z,a1.w))),
                         fminf(fminf(fminf(a2.x,a2.y),fminf(a2.z,a2.w)),
                               fminf(fminf(a3.x,a3.y),fminf(a3.z,a3.w))));
        #pragma unroll
        for (int m = 0; m < 4; ++m) {
          const int msk = (m<2) ? (1<<m) : (1<<(m+2));   // 1,2,16,32
          sm += __shfl_xor(sm, msk);
          mx = fmaxf(mx, __shfl_xor(mx, msk));
          mn = fminf(mn, __shfl_xor(mn, msk));
        }
        if (lane < 16 && (lane & 3) == 0) {
          int cj = lane >> 2;
          scr[(ci*4+cj)*3+0] = sm * (1.0f/256.0f);
          scr[(ci*4+cj)*3+1] = mx;
          scr[(ci*4+cj)*3+2] = mn;
        }
      }
      #pragma unroll
      for (int cell = 0; cell < 16; ++cell) {
        float vv = scr[cell*3]*wd0 + scr[cell*3+1]*wd1 + scr[cell*3+2]*wd2 + bde;
        emb2b[(((size_t)t*16 + cell)*256 + bid)*64 + lane] = f2bf(fmaxf(vv, 0.f));
      }
    }
  }

  // ---------- prologue B: pack Ws / W_ho into LDS as bf16 B-frags ----------
  __syncthreads();
  for (int s = tid; s < 1024; s += 512) {
    int wv = s >> 8, kt = (s >> 6) & 3, ln = s & 63;
    int e = wv*16 + (ln & 15), kb = kt*32 + (ln >> 4)*8;
    const float* src = Ws + (size_t)n*8192 + (size_t)kb*64 + e;
    bf16x8 v;
    #pragma unroll
    for (int j = 0; j < 8; ++j) v[j] = (short)f2bf(src[(size_t)j*64]);
    *(bf16x8*)&sWsF[s*16] = v;
  }
  for (int s = tid; s < 2048; s += 512) {
    int wv = s >> 8, kt = (s >> 6) & 3, ln = s & 63;
    int o = wv*16 + (ln & 15), kb = kt*32 + (ln >> 4)*8;
    const float* src = W_ho + (size_t)n*16384 + (size_t)kb*128 + o;
    bf16x8 v;
    #pragma unroll
    for (int j = 0; j < 8; ++j) v[j] = (short)f2bf(src[(size_t)j*128]);
    *(bf16x8*)&sWoF[s*16] = v;
  }

  // ---------- prologue C: resident bf16 gate B-frags + biases ----------
  const int hcol = w*16 + (lane & 15);
  bf16x8 bw[4][8];
  float bias[4];
  {
    const int krow = (lane >> 4)*8;
    #pragma unroll
    for (int G = 0; G < 4; ++G) {
      const float* srcI = W_ih + ((size_t)n*512 + G*128 + hcol)*128;
      const float* srcH = W_hh + ((size_t)n*512 + G*128 + hcol)*128;
      #pragma unroll
      for (int kt = 0; kt < 8; ++kt) {
        const float* s = (kt < 4) ? (srcI + kt*32 + krow) : (srcH + (kt-4)*32 + krow);
        float4 aa = *(const float4*)s;
        float4 bb = *(const float4*)(s+4);
        bf16x8 v;
        v[0]=(short)f2bf(aa.x); v[1]=(short)f2bf(aa.y); v[2]=(short)f2bf(aa.z); v[3]=(short)f2bf(aa.w);
        v[4]=(short)f2bf(bb.x); v[5]=(short)f2bf(bb.y); v[6]=(short)f2bf(bb.z); v[7]=(short)f2bf(bb.w);
        bw[G][kt] = v;
      }
      int gg = n*512 + G*128 + hcol;
      bias[G] = b_ih[gg] + b_hh[gg];
    }
  }
  // zero the h region of sXb (h0 = 0)
  { int b = tid >> 5, j = tid & 31;
    *(uint2*)&sXb[ax(b, 256 + j*8)] = make_uint2(0u, 0u); }

  asm volatile("s_waitcnt vmcnt(0)" ::: "memory");   // flag zeroes drained
  grid.sync();

  // ---------- per-thread maps ----------
  const int ocol = w*16 + (lane & 15);
  const float bho = b_ho[n*128 + ocol], wout = W_out[ocol];
  const float bout = b_out[0];
  const int sb = tid >> 5, sj = tid & 31, se2 = sj*2;
  const float bs0 = bs[se2], bs1 = bs[se2+1];
  float creg[4] = {0.f, 0.f, 0.f, 0.f};
  const int ab = lane & 15, akb = (lane >> 4)*16;

  // stage emb[t=0] into buffer 0
  { unsigned v = *(const unsigned*)&emb2b[(((size_t)0*16 + n)*256 + b0c + sb)*64 + se2];
    *(unsigned*)&sEmbD[axe(sb, sj*4)] = v; }
  __syncthreads();

  for (int t = 0; t < 48; ++t) {
    const unsigned char* sEmb = sEmbD + (t&1)*2048;

    // ---- stage emb[t+1] into the other buffer (ordered vs next-step reads by B2/B3/B4) ----
    if (t < 47) {
      unsigned v = *(const unsigned*)&emb2b[(((size_t)(t+1)*16 + n)*256 + b0c + sb)*64 + se2];
      *(unsigned*)&sEmbD[((t+1)&1)*2048 + axe(sb, sj*4)] = v;
    }

    // ---- gates partial MFMA: kt {0,1} (emb) + {4..7} (h) — block-local ----
    f32x4 acc[4];
    #pragma unroll
    for (int G = 0; G < 4; ++G) { f32x4 c0 = {bias[G], bias[G], bias[G], bias[G]}; acc[G] = c0; }
    #pragma unroll
    for (int kt = 0; kt < 2; ++kt) {
      bf16x8 aF = *(const bf16x8*)&sEmb[axe(ab, kt*64 + akb)];
      #pragma unroll
      for (int G = 0; G < 4; ++G)
        acc[G] = __builtin_amdgcn_mfma_f32_16x16x32_bf16(aF, bw[G][kt], acc[G], 0, 0, 0);
    }
    #pragma unroll
    for (int kt = 4; kt < 8; ++kt) {
      bf16x8 aF = *(const bf16x8*)&sXb[ax(ab, kt*64 + akb)];
      #pragma unroll
      for (int G = 0; G < 4; ++G)
        acc[G] = __builtin_amdgcn_mfma_f32_16x16x32_bf16(aF, bw[G][kt], acc[G], 0, 0, 0);
    }

    // ---- poll previous step's 64 per-wave flags ----
    if (t > 0 && tid < 64) {
      const int* fp = &flagv[(((t-1)*16 + bt)*64 + tid)*4];
      int f0 = __hip_atomic_load(fp, __ATOMIC_RELAXED, __HIP_MEMORY_SCOPE_AGENT);
      while (!f0) {
        __builtin_amdgcn_s_sleep(1);
        f0 = __hip_atomic_load(fp, __ATOMIC_RELAXED, __HIP_MEMORY_SCOPE_AGENT);
      }
    }
    __syncthreads();                                     // B2: producers done; prev red[] complete

    // ---- social loads issued first; y-reduce(t-1) hides under the RTT ----
    { float s0 = bs0, s1 = bs1;
      unsigned long long v[16];
      if (t > 0) {
        const unsigned long long* pb = (const unsigned long long*)
          (psoc + (size_t)((t-1)&1)*1048576 + (size_t)(b0c + sb)*64 + se2);
        #pragma unroll
        for (int nn = 0; nn < 16; ++nn)
          v[nn] = __hip_atomic_load(pb + (size_t)nn*8192, __ATOMIC_RELAXED, __HIP_MEMORY_SCOPE_AGENT);
      }
      // y-reduce for step t-1 (reads red[] written before B2)
      if (t > 0 && tid < 256) {
        int bb = tid >> 4, l = tid & 15;
        float sm2 = 0.f;
        #pragma unroll
        for (int kk = 0; kk < 8; ++kk) sm2 += red[bb*132 + l + 16*kk];
        #pragma unroll
        for (int m = 8; m >= 1; m >>= 1) sm2 += __shfl_xor(sm2, m, 16);
        if (l == 0) y[((size_t)(t-1)*256 + b0c + bb)*16 + n] = sm2 + bout;
      }
      if (t > 0) {
        #pragma unroll
        for (int nn = 0; nn < 16; ++nn) {
          float2 f2 = __builtin_bit_cast(float2, v[nn]);
          s0 += f2.x; s1 += f2.y;
        }
      }
      unsigned pk = (unsigned)f2bf(fmaxf(s0,0.f)) | ((unsigned)f2bf(fmaxf(s1,0.f)) << 16);
      *(unsigned*)&sXb[ax(sb, 128 + sj*4)] = pk; }
    __syncthreads();                                     // B3: social visible

    // ---- gates MFMA kt {2,3} (social) ----
    #pragma unroll
    for (int kt = 2; kt < 4; ++kt) {
      bf16x8 aF = *(const bf16x8*)&sXb[ax(ab, kt*64 + akb)];
      #pragma unroll
      for (int G = 0; G < 4; ++G)
        acc[G] = __builtin_amdgcn_mfma_f32_16x16x32_bf16(aF, bw[G][kt], acc[G], 0, 0, 0);
    }

    // ---- LSTM cell; write h (bf16) ----
    #pragma unroll
    for (int r = 0; r < 4; ++r) {
      int b = (lane >> 4)*4 + r;
      float cn = sigf(acc[1][r])*creg[r] + sigf(acc[0][r])*tanh_f(acc[2][r]);
      float hn = sigf(acc[3][r])*tanh_f(cn);
      creg[r] = cn;
      *(unsigned short*)&sXb[ax(b, 256 + hcol*2)] = f2bf(hn);
    }
    __syncthreads();                                     // B4: new h visible

    // ---- load h frags once ----
    bf16x8 aH[4];
    #pragma unroll
    for (int kt = 0; kt < 4; ++kt)
      aH[kt] = *(const bf16x8*)&sXb[ax(ab, 256 + kt*64 + akb)];

    // ---- waves 0-3: social MFMA -> psoc stores -> drain -> FLAG (before head MFMA) ----
    if (w < 4) {
      f32x4 ps = {0.f, 0.f, 0.f, 0.f};
      #pragma unroll
      for (int kt = 0; kt < 4; ++kt) {
        bf16x8 bs_ = *(const bf16x8*)&sWsF[((w*4 + kt)*64 + lane)*16];
        ps = __builtin_amdgcn_mfma_f32_16x16x32_bf16(aH[kt], bs_, ps, 0, 0, 0);
      }
      if (t < 47) {
        float* pw = psoc + (size_t)(t&1)*1048576 + (size_t)n*16384;
        const int ecol = w*16 + (lane & 15);
        #pragma unroll
        for (int r = 0; r < 4; ++r) {
          int b = b0c + (lane >> 4)*4 + r;
          __hip_atomic_store(&pw[(size_t)b*64 + ecol], ps[r], __ATOMIC_RELAXED, __HIP_MEMORY_SCOPE_AGENT);
        }
        asm volatile("s_waitcnt vmcnt(0)" ::: "memory");   // this wave's stores at coherence point
        if (lane == 0)
          __hip_atomic_store(&flagv[((t*16 + bt)*64 + n*4 + w)*4], 1,
                             __ATOMIC_RELAXED, __HIP_MEMORY_SCOPE_AGENT);
      }
    }

    // ---- head MFMA (all waves) + epilogue into red ----
    f32x4 ph = {bho, bho, bho, bho};
    #pragma unroll
    for (int kt = 0; kt < 4; ++kt) {
      bf16x8 bo = *(const bf16x8*)&sWoF[((w*4 + kt)*64 + lane)*16];
      ph = __builtin_amdgcn_mfma_f32_16x16x32_bf16(aH[kt], bo, ph, 0, 0, 0);
    }
    #pragma unroll
    for (int r = 0; r < 4; ++r) {
      int b = (lane >> 4)*4 + r;
      red[b*132 + ocol] = wout * sigf(ph[r]);
    }
    // no end-of-step barrier: next step's B2 orders red[] writes vs y-reduce reads
  }

  // ---- final y-reduce for t = 47 ----
  __syncthreads();
  if (tid < 256) {
    int bb = tid >> 4, l = tid & 15;
    float sm2 = 0.f;
    #pragma unroll
    for (int kk = 0; kk < 8; ++kk) sm2 += red[bb*132 + l + 16*kk];
    #pragma unroll
    for (int m = 8; m >= 1; m >>= 1) sm2 += __shfl_xor(sm2, m, 16);
    if (l == 0) y[((size_t)47*256 + b0c + bb)*16 + n] = sm2 + bout;
  }
}

extern "C" void kernel_launch(void* const* d_in, const int* in_sizes, int n_in,
                              void* d_out, int out_size, void* d_ws, size_t ws_size,
                              hipStream_t stream){
  const float* x    = (const float*)d_in[0];
  const float* Wd   = (const float*)d_in[1];
  const float* bd   = (const float*)d_in[2];
  const float* Ws   = (const float*)d_in[3];
  const float* bs   = (const float*)d_in[4];
  const float* W_ih = (const float*)d_in[5];
  const float* b_ih = (const float*)d_in[6];
  const float* W_hh = (const float*)d_in[7];
  const float* b_hh = (const float*)d_in[8];
  const float* W_ho = (const float*)d_in[9];
  const float* b_ho = (const float*)d_in[10];
  const float* W_out= (const float*)d_in[11];
  const float* b_out= (const float*)d_in[12];
  float* y = (float*)d_out;

  char* ws = (char*)d_ws;
  unsigned short* emb2b = (unsigned short*)ws;          // 25,165,824 B
  float* psoc  = (float*)(ws + 25165824);               // 8,388,608 B (2 buf)
  int*   flagv = (int*)(ws + 25165824 + 8388608);       // 196,608 B (48*16*64 slots, 16B padded)

  hipFuncSetAttribute((const void*)k_fused, hipFuncAttributeMaxDynamicSharedMemorySize, SMEM_BYTES);

  void* args[] = { (void*)&x, (void*)&Wd, (void*)&bd, (void*)&Ws, (void*)&bs,
                   (void*)&W_ih, (void*)&b_ih, (void*)&W_hh, (void*)&b_hh,
                   (void*)&W_ho, (void*)&b_ho, (void*)&W_out, (void*)&b_out,
                   (void*)&y, (void*)&emb2b, (void*)&psoc, (void*)&flagv };
  hipLaunchCooperativeKernel((const void*)k_fused, dim3(256), dim3(512), args, SMEM_BYTES, stream);
}

// Round 16
// 311.109 us; speedup vs baseline: 1.7953x; 1.0106x over previous
//
#include <hip/hip_runtime.h>
#include <hip/hip_cooperative_groups.h>
#include <cmath>

namespace cg = cooperative_groups;

// B=256, T=48, N2=16, E=64, H=128, G=4H=512
// Block = (node n, batch-tile bt of 16). Proven protocol: psoc sc1 data slots,
// per-wave producer flags (own vmcnt drain + lane0 store), 64-lane poll,
// 3 barriers/step, y-reduce(t-1)+emb-stage folded under mailbox RTT.
// This round: psoc repacked [n][bt][e][16b] -> producer = ONE 16B sc1 store
// per thread; consumer remapped to (e, b-pair) threads (coalesced loads).

typedef __attribute__((ext_vector_type(8))) short bf16x8;
typedef __attribute__((ext_vector_type(4))) float f32x4;

__device__ __forceinline__ float fexp2(float x){ return __builtin_amdgcn_exp2f(x); }
__device__ __forceinline__ float frcp(float x){ return __builtin_amdgcn_rcpf(x); }
__device__ __forceinline__ float sigf(float x){ return frcp(1.0f + fexp2(-1.44269504f*x)); }
__device__ __forceinline__ float tanh_f(float x){ return 1.0f - 2.0f*frcp(1.0f + fexp2(2.88539008f*x)); }
__device__ __forceinline__ unsigned short f2bf(float f){
  unsigned u = __builtin_bit_cast(unsigned, f);
  return (unsigned short)((u + 0x7FFFu + ((u>>16)&1u)) >> 16);
}
__device__ __forceinline__ int ax(int b, int kb){ return (b<<9) + (kb ^ ((b&7)<<4)); }
__device__ __forceinline__ int axe(int b, int kb){ return (b<<7) + (kb ^ ((b&7)<<4)); }

// dynamic LDS partition (bytes)
#define OFF_WOF 0        // 32768: head B-frags
#define OFF_WSF 32768    // 16384: social B-frags
#define OFF_XB  49152    // 8192:  sXb bf16 [b][k=256] swizzled (pad|social|h)
#define OFF_EMB 57344    // 4096:  sEmbD: 2 x [16][128B] swizzled
#define OFF_RED 61440    // 8448:  red[16][132] fp32 (+ prologue scratch)
#define SMEM_BYTES 69888

__global__ __launch_bounds__(512, 2) void k_fused(
    const float* __restrict__ x, const float* __restrict__ Wd, const float* __restrict__ bd,
    const float* __restrict__ Ws, const float* __restrict__ bs,
    const float* __restrict__ W_ih, const float* __restrict__ b_ih,
    const float* __restrict__ W_hh, const float* __restrict__ b_hh,
    const float* __restrict__ W_ho, const float* __restrict__ b_ho,
    const float* __restrict__ W_out, const float* __restrict__ b_out,
    float* __restrict__ y,
    unsigned short* __restrict__ emb2b, float* __restrict__ psoc, int* __restrict__ flagv)
{
  extern __shared__ unsigned char smem[];
  unsigned char* sWoF  = smem + OFF_WOF;
  unsigned char* sWsF  = smem + OFF_WSF;
  unsigned char* sXb   = smem + OFF_XB;
  unsigned char* sEmbD = smem + OFF_EMB;
  float* red           = (float*)(smem + OFF_RED);

  const int bid = blockIdx.x, tid = threadIdx.x;
  const int lane = tid & 63, w = tid >> 6;
  cg::grid_group grid = cg::this_grid();

  const int n  = ((bid & 7) << 1) | ((bid >> 3) & 1);
  const int bt = bid >> 4, b0c = bt*16;

  // ---- zero my per-wave flag slots: [t][bt][n][w], 16B padded ----
  for (int j = tid; j < 192; j += 512)   // j = t*4 + w
    __hip_atomic_store(&flagv[(((j>>2)*16 + bt)*64 + n*4 + (j&3))*4], 0,
                       __ATOMIC_RELAXED, __HIP_MEMORY_SCOPE_AGENT);

  // ---------- prologue A: downsample + embed, barrier-free (wave w: t = w+8*it) ----------
  {
    const float wd0 = Wd[lane], wd1 = Wd[64+lane], wd2 = Wd[128+lane], bde = bd[lane];
    float* scr = red + w*64;   // per-wave scratch
    for (int it = 0; it < 6; ++it) {
      const int t = w + it*8;
      const float* xp = x + ((size_t)bid*48 + t)*4096;
      float4 xv[4][4];
      #pragma unroll
      for (int ci = 0; ci < 4; ++ci) {           // hoist all 16 loads
        const float* rp = xp + (16*ci + (lane>>4))*64 + (lane&15)*4;
        xv[ci][0] = *(const float4*)(rp);
        xv[ci][1] = *(const float4*)(rp + 256);
        xv[ci][2] = *(const float4*)(rp + 512);
        xv[ci][3] = *(const float4*)(rp + 768);
      }
      #pragma unroll
      for (int ci = 0; ci < 4; ++ci) {
        float4 a0 = xv[ci][0], a1 = xv[ci][1], a2 = xv[ci][2], a3 = xv[ci][3];
        float sm = a0.x+a0.y+a0.z+a0.w + a1.x+a1.y+a1.z+a1.w
                 + a2.x+a2.y+a2.z+a2.w + a3.x+a3.y+a3.z+a3.w;
        float mx = fmaxf(fmaxf(fmaxf(fmaxf(a0.x,a0.y),fmaxf(a0.z,a0.w)),
                               fmaxf(fmaxf(a1.x,a1.y),fmaxf(a1.z,a1.w))),
                         fmaxf(fmaxf(fmaxf(a2.x,a2.y),fmaxf(a2.z,a2.w)),
                               fmaxf(fmaxf(a3.x,a3.y),fmaxf(a3.z,a3.w))));
        float mn = fminf(fminf(fminf(fminf(a0.x,a0.y),fminf(a0.z,a0.w)),
                               fminf(fminf(a1.x,a1.y),fminf(a1.z,a1.w))),
                         fminf(fminf(fminf(a2.x,a2.y),fminf(a2.z,a2.w)),
                               fminf(fminf(a3.x,a3.y),fminf(a3.z,a3.w))));
        #pragma unroll
        for (int m = 0; m < 4; ++m) {
          const int msk = (m<2) ? (1<<m) : (1<<(m+2));   // 1,2,16,32
          sm += __shfl_xor(sm, msk);
          mx = fmaxf(mx, __shfl_xor(mx, msk));
          mn = fminf(mn, __shfl_xor(mn, msk));
        }
        if (lane < 16 && (lane & 3) == 0) {
          int cj = lane >> 2;
          scr[(ci*4+cj)*3+0] = sm * (1.0f/256.0f);
          scr[(ci*4+cj)*3+1] = mx;
          scr[(ci*4+cj)*3+2] = mn;
        }
      }
      #pragma unroll
      for (int cell = 0; cell < 16; ++cell) {
        float vv = scr[cell*3]*wd0 + scr[cell*3+1]*wd1 + scr[cell*3+2]*wd2 + bde;
        emb2b[(((size_t)t*16 + cell)*256 + bid)*64 + lane] = f2bf(fmaxf(vv, 0.f));
      }
    }
  }

  // ---------- prologue B: pack Ws / W_ho into LDS as bf16 B-frags ----------
  __syncthreads();
  for (int s = tid; s < 1024; s += 512) {
    int wv = s >> 8, kt = (s >> 6) & 3, ln = s & 63;
    int e = wv*16 + (ln & 15), kb = kt*32 + (ln >> 4)*8;
    const float* src = Ws + (size_t)n*8192 + (size_t)kb*64 + e;
    bf16x8 v;
    #pragma unroll
    for (int j = 0; j < 8; ++j) v[j] = (short)f2bf(src[(size_t)j*64]);
    *(bf16x8*)&sWsF[s*16] = v;
  }
  for (int s = tid; s < 2048; s += 512) {
    int wv = s >> 8, kt = (s >> 6) & 3, ln = s & 63;
    int o = wv*16 + (ln & 15), kb = kt*32 + (ln >> 4)*8;
    const float* src = W_ho + (size_t)n*16384 + (size_t)kb*128 + o;
    bf16x8 v;
    #pragma unroll
    for (int j = 0; j < 8; ++j) v[j] = (short)f2bf(src[(size_t)j*128]);
    *(bf16x8*)&sWoF[s*16] = v;
  }

  // ---------- prologue C: resident bf16 gate B-frags + biases ----------
  const int hcol = w*16 + (lane & 15);
  bf16x8 bw[4][8];
  float bias[4];
  {
    const int krow = (lane >> 4)*8;
    #pragma unroll
    for (int G = 0; G < 4; ++G) {
      const float* srcI = W_ih + ((size_t)n*512 + G*128 + hcol)*128;
      const float* srcH = W_hh + ((size_t)n*512 + G*128 + hcol)*128;
      #pragma unroll
      for (int kt = 0; kt < 8; ++kt) {
        const float* s = (kt < 4) ? (srcI + kt*32 + krow) : (srcH + (kt-4)*32 + krow);
        float4 aa = *(const float4*)s;
        float4 bb = *(const float4*)(s+4);
        bf16x8 v;
        v[0]=(short)f2bf(aa.x); v[1]=(short)f2bf(aa.y); v[2]=(short)f2bf(aa.z); v[3]=(short)f2bf(aa.w);
        v[4]=(short)f2bf(bb.x); v[5]=(short)f2bf(bb.y); v[6]=(short)f2bf(bb.z); v[7]=(short)f2bf(bb.w);
        bw[G][kt] = v;
      }
      int gg = n*512 + G*128 + hcol;
      bias[G] = b_ih[gg] + b_hh[gg];
    }
  }
  // zero the h region of sXb (h0 = 0)
  { int b = tid >> 5, j = tid & 31;
    *(uint2*)&sXb[ax(b, 256 + j*8)] = make_uint2(0u, 0u); }

  asm volatile("s_waitcnt vmcnt(0)" ::: "memory");   // flag zeroes drained
  grid.sync();

  // ---------- per-thread maps ----------
  const int ocol = w*16 + (lane & 15);
  const float bho = b_ho[n*128 + ocol], wout = W_out[ocol];
  const float bout = b_out[0];
  const int sb = tid >> 5, sj = tid & 31, se2 = sj*2;   // emb staging map
  const int ce = tid >> 3, cbp = tid & 7;               // social consume map (e, b-pair)
  const float bsc = bs[ce];
  float creg[4] = {0.f, 0.f, 0.f, 0.f};
  const int ab = lane & 15, akb = (lane >> 4)*16;

  // stage emb[t=0] into buffer 0
  { unsigned v = *(const unsigned*)&emb2b[(((size_t)0*16 + n)*256 + b0c + sb)*64 + se2];
    *(unsigned*)&sEmbD[axe(sb, sj*4)] = v; }
  __syncthreads();

  for (int t = 0; t < 48; ++t) {
    const unsigned char* sEmb = sEmbD + (t&1)*2048;

    // ---- stage emb[t+1] into the other buffer (ordered vs next-step reads by B2/B3/B4) ----
    if (t < 47) {
      unsigned v = *(const unsigned*)&emb2b[(((size_t)(t+1)*16 + n)*256 + b0c + sb)*64 + se2];
      *(unsigned*)&sEmbD[((t+1)&1)*2048 + axe(sb, sj*4)] = v;
    }

    // ---- gates partial MFMA: kt {0,1} (emb) + {4..7} (h) — block-local ----
    f32x4 acc[4];
    #pragma unroll
    for (int G = 0; G < 4; ++G) { f32x4 c0 = {bias[G], bias[G], bias[G], bias[G]}; acc[G] = c0; }
    #pragma unroll
    for (int kt = 0; kt < 2; ++kt) {
      bf16x8 aF = *(const bf16x8*)&sEmb[axe(ab, kt*64 + akb)];
      #pragma unroll
      for (int G = 0; G < 4; ++G)
        acc[G] = __builtin_amdgcn_mfma_f32_16x16x32_bf16(aF, bw[G][kt], acc[G], 0, 0, 0);
    }
    #pragma unroll
    for (int kt = 4; kt < 8; ++kt) {
      bf16x8 aF = *(const bf16x8*)&sXb[ax(ab, kt*64 + akb)];
      #pragma unroll
      for (int G = 0; G < 4; ++G)
        acc[G] = __builtin_amdgcn_mfma_f32_16x16x32_bf16(aF, bw[G][kt], acc[G], 0, 0, 0);
    }

    // ---- poll previous step's 64 per-wave flags ----
    if (t > 0 && tid < 64) {
      const int* fp = &flagv[(((t-1)*16 + bt)*64 + tid)*4];
      int f0 = __hip_atomic_load(fp, __ATOMIC_RELAXED, __HIP_MEMORY_SCOPE_AGENT);
      while (!f0) {
        __builtin_amdgcn_s_sleep(1);
        f0 = __hip_atomic_load(fp, __ATOMIC_RELAXED, __HIP_MEMORY_SCOPE_AGENT);
      }
    }
    __syncthreads();                                     // B2: producers done; prev red[] complete

    // ---- social loads issued first; y-reduce(t-1) hides under the RTT ----
    { float s0 = bsc, s1 = bsc;
      unsigned long long v[16];
      if (t > 0) {
        // psoc layout: [buf][n][bt][e][16b] fp32; n-stride = 16*64*16 = 16384 floats
        const unsigned long long* pb = (const unsigned long long*)
          (psoc + (size_t)((t-1)&1)*262144 + ((size_t)bt*64 + ce)*16 + cbp*2);
        #pragma unroll
        for (int nn = 0; nn < 16; ++nn)
          v[nn] = __hip_atomic_load(pb + (size_t)nn*8192, __ATOMIC_RELAXED, __HIP_MEMORY_SCOPE_AGENT);
      }
      // y-reduce for step t-1 (reads red[] written before B2)
      if (t > 0 && tid < 256) {
        int bb = tid >> 4, l = tid & 15;
        float sm2 = 0.f;
        #pragma unroll
        for (int kk = 0; kk < 8; ++kk) sm2 += red[bb*132 + l + 16*kk];
        #pragma unroll
        for (int m = 8; m >= 1; m >>= 1) sm2 += __shfl_xor(sm2, m, 16);
        if (l == 0) y[((size_t)(t-1)*256 + b0c + bb)*16 + n] = sm2 + bout;
      }
      if (t > 0) {
        #pragma unroll
        for (int nn = 0; nn < 16; ++nn) {
          float2 f2 = __builtin_bit_cast(float2, v[nn]);
          s0 += f2.x; s1 += f2.y;
        }
      }
      // stage social bf16: rows b=2cbp, 2cbp+1, col ce
      *(unsigned short*)&sXb[ax(2*cbp,   128 + ce*2)] = f2bf(fmaxf(s0, 0.f));
      *(unsigned short*)&sXb[ax(2*cbp+1, 128 + ce*2)] = f2bf(fmaxf(s1, 0.f)); }
    __syncthreads();                                     // B3: social visible

    // ---- gates MFMA kt {2,3} (social) ----
    #pragma unroll
    for (int kt = 2; kt < 4; ++kt) {
      bf16x8 aF = *(const bf16x8*)&sXb[ax(ab, kt*64 + akb)];
      #pragma unroll
      for (int G = 0; G < 4; ++G)
        acc[G] = __builtin_amdgcn_mfma_f32_16x16x32_bf16(aF, bw[G][kt], acc[G], 0, 0, 0);
    }

    // ---- LSTM cell; write h (bf16) ----
    #pragma unroll
    for (int r = 0; r < 4; ++r) {
      int b = (lane >> 4)*4 + r;
      float cn = sigf(acc[1][r])*creg[r] + sigf(acc[0][r])*tanh_f(acc[2][r]);
      float hn = sigf(acc[3][r])*tanh_f(cn);
      creg[r] = cn;
      *(unsigned short*)&sXb[ax(b, 256 + hcol*2)] = f2bf(hn);
    }
    __syncthreads();                                     // B4: new h visible

    // ---- load h frags once ----
    bf16x8 aH[4];
    #pragma unroll
    for (int kt = 0; kt < 4; ++kt)
      aH[kt] = *(const bf16x8*)&sXb[ax(ab, 256 + kt*64 + akb)];

    // ---- waves 0-3: social MFMA -> ONE 16B psoc store -> drain -> FLAG ----
    if (w < 4) {
      f32x4 ps = {0.f, 0.f, 0.f, 0.f};
      #pragma unroll
      for (int kt = 0; kt < 4; ++kt) {
        bf16x8 bs_ = *(const bf16x8*)&sWsF[((w*4 + kt)*64 + lane)*16];
        ps = __builtin_amdgcn_mfma_f32_16x16x32_bf16(aH[kt], bs_, ps, 0, 0, 0);
      }
      if (t < 47) {
        // ps[r] = psoc value for (b = b0c + (lane>>4)*4 + r, e = ecol): contiguous in new layout
        const int ecol = w*16 + (lane & 15);
        float* pw = psoc + (size_t)(t&1)*262144
                  + (((size_t)n*16 + bt)*64 + ecol)*16 + (lane >> 4)*4;
        asm volatile("global_store_dwordx4 %0, %1, off sc1" :: "v"(pw), "v"(ps) : "memory");
        asm volatile("s_waitcnt vmcnt(0)" ::: "memory");   // this wave's store at coherence point
        if (lane == 0)
          __hip_atomic_store(&flagv[((t*16 + bt)*64 + n*4 + w)*4], 1,
                             __ATOMIC_RELAXED, __HIP_MEMORY_SCOPE_AGENT);
      }
    }

    // ---- head MFMA (all waves) + epilogue into red ----
    f32x4 ph = {bho, bho, bho, bho};
    #pragma unroll
    for (int kt = 0; kt < 4; ++kt) {
      bf16x8 bo = *(const bf16x8*)&sWoF[((w*4 + kt)*64 + lane)*16];
      ph = __builtin_amdgcn_mfma_f32_16x16x32_bf16(aH[kt], bo, ph, 0, 0, 0);
    }
    #pragma unroll
    for (int r = 0; r < 4; ++r) {
      int b = (lane >> 4)*4 + r;
      red[b*132 + ocol] = wout * sigf(ph[r]);
    }
    // no end-of-step barrier: next step's B2 orders red[] writes vs y-reduce reads
  }

  // ---- final y-reduce for t = 47 ----
  __syncthreads();
  if (tid < 256) {
    int bb = tid >> 4, l = tid & 15;
    float sm2 = 0.f;
    #pragma unroll
    for (int kk = 0; kk < 8; ++kk) sm2 += red[bb*132 + l + 16*kk];
    #pragma unroll
    for (int m = 8; m >= 1; m >>= 1) sm2 += __shfl_xor(sm2, m, 16);
    if (l == 0) y[((size_t)47*256 + b0c + bb)*16 + n] = sm2 + bout;
  }
}

extern "C" void kernel_launch(void* const* d_in, const int* in_sizes, int n_in,
                              void* d_out, int out_size, void* d_ws, size_t ws_size,
                              hipStream_t stream){
  const float* x    = (const float*)d_in[0];
  const float* Wd   = (const float*)d_in[1];
  const float* bd   = (const float*)d_in[2];
  const float* Ws   = (const float*)d_in[3];
  const float* bs   = (const float*)d_in[4];
  const float* W_ih = (const float*)d_in[5];
  const float* b_ih = (const float*)d_in[6];
  const float* W_hh = (const float*)d_in[7];
  const float* b_hh = (const float*)d_in[8];
  const float* W_ho = (const float*)d_in[9];
  const float* b_ho = (const float*)d_in[10];
  const float* W_out= (const float*)d_in[11];
  const float* b_out= (const float*)d_in[12];
  float* y = (float*)d_out;

  char* ws = (char*)d_ws;
  unsigned short* emb2b = (unsigned short*)ws;          // 25,165,824 B
  float* psoc  = (float*)(ws + 25165824);               // 2 buf x 262144 floats
  int*   flagv = (int*)(ws + 25165824 + 8388608);       // 196,608 B (48*16*64 slots, 16B padded)

  hipFuncSetAttribute((const void*)k_fused, hipFuncAttributeMaxDynamicSharedMemorySize, SMEM_BYTES);

  void* args[] = { (void*)&x, (void*)&Wd, (void*)&bd, (void*)&Ws, (void*)&bs,
                   (void*)&W_ih, (void*)&b_ih, (void*)&W_hh, (void*)&b_hh,
                   (void*)&W_ho, (void*)&b_ho, (void*)&W_out, (void*)&b_out,
                   (void*)&y, (void*)&emb2b, (void*)&psoc, (void*)&flagv };
  hipLaunchCooperativeKernel((const void*)k_fused, dim3(256), dim3(512), args, SMEM_BYTES, stream);
}